// Round 9
// baseline (681.849 us; speedup 1.0000x reference)
//
#include <hip/hip_runtime.h>

// FindInstancePeaks: fused conv backbone + global peak finding.
// crops (128,192,192,1) f32 -> conv1 3x3 s2 SAME (1->32) + relu
//                          -> conv2 3x3 s1 SAME (32->17) = cms (128,96,96,17)
// -> per (b,n): argmax over 96x96, quarter-pixel sign refine, *2, NaN<0.2.
//
// R17: corrected issue-slot model (conv2 = 14,688 FMA/thread; per-SIMD
// ~240k slot-cycles: FMA-datapath 176k + s_load 29k + conv1 12k + LDS 12k)
// explains R10-R16: the kernel is slot-bound; only fewer multiplies help.
// => 1-D Winograd F(2,3) along x on conv2 (exact in real arithmetic,
// ~1e-6 reassociation error):
//  - per pair per (c,ky): m_j = t_j * g~_j, 4 muls vs 6; data transform
//    t (4 adds) amortized over 17 channels; weight transform g~ hoisted
//    to a setup kernel writing d_ws (SALU has no FP).
//  - 4 px/thread (2 pairs), 192-thread blocks, SAME 24x32 tile, grid
//    1536 (3 blocks/CU = 2 exact rounds). s_load stays 17/px.
//  - macc[17][2][4]=136 VGPR; __launch_bounds__(192,2) -> cap 256, no
//    spill risk. HSTR 29 keeps conv2 reads ~2-way bank-aliased (free).
// Slot model: 240k -> ~195k/SIMD. Output transform o0=m0+m1+m2,
// o1=m1-m2-m3 applied once per n in the epilogue.

#define NCH 17
#define C1 32
#define TW 24           // tile width
#define TH 32           // tile height
#define HT_W 26         // h cols needed (TW+2)
#define HT_H 34         // h rows needed (TH+2)
#define HSTR 29         // s_h col stride (29: conv2 read pattern ~2-way/bank)
#define IN_W 53         // input patch cols: 2*HT_W+1
#define IN_H 69         // input patch rows: 2*HT_H+1
#define CG 8            // conv1 channels per group
#define NG 4            // groups
#define NT 192          // threads per block (4 px/thread)
#define NHPX (HT_H * HT_W)   // 884 h-pixels per block
#define SH_PLANE (HT_H * HSTR)
#define WT_OFF 17408    // byte offset of transformed weights in d_ws

__device__ __forceinline__ unsigned long long pack_key(float v, unsigned flat) {
    unsigned ub = __float_as_uint(v);
    ub = (ub & 0x80000000u) ? ~ub : (ub | 0x80000000u);   // monotone float->uint
    return ((unsigned long long)ub << 32) | (unsigned)(~flat); // ~flat: ties -> lowest idx
}

// g~[ky][c][j][n], j=0..3: F(2,3) weight transform of W2 (HWIO 3,3,32,17).
__global__ void wt_setup_kernel(const float* __restrict__ W2g,
                                float* __restrict__ Wt) {
    int i = blockIdx.x * 256 + threadIdx.x;    // over 3*32*17
    if (i >= 3 * C1 * NCH) return;
    int n = i % NCH, rem = i / NCH;
    int c = rem % C1, ky = rem / C1;
    float g0 = W2g[((ky * 3 + 0) * C1 + c) * NCH + n];
    float g1 = W2g[((ky * 3 + 1) * C1 + c) * NCH + n];
    float g2 = W2g[((ky * 3 + 2) * C1 + c) * NCH + n];
    float* o = Wt + ((ky * C1 + c) * 4) * NCH + n;
    o[0 * NCH] = g0;
    o[1 * NCH] = 0.5f * (g0 + g1 + g2);
    o[2 * NCH] = 0.5f * (g0 - g1 + g2);
    o[3 * NCH] = g2;
}

__global__ __launch_bounds__(NT, 2) void conv_peaks_kernel(
    const float* __restrict__ crops, const float* __restrict__ W1g,
    const float* __restrict__ b1g, const float* __restrict__ Wtg,
    const float* __restrict__ b2g, unsigned long long* __restrict__ peaks) {
    __shared__ __align__(16) float s_in[IN_H * IN_W];        // 14628 B
    __shared__ __align__(16) float s_h[CG * SH_PLANE];       // 31552 B

    const int t = threadIdx.x;
    const int b = blockIdx.y;
    const int ty0 = (blockIdx.x >> 2) * TH;   // 0,32,64
    const int tx0 = (blockIdx.x & 3) * TW;    // 0,24,48,72
    const int iy0 = 2 * ty0 - 2;
    const int ix0 = 2 * tx0 - 2;
    const float* cb = crops + b * 192 * 192;

    // --- stage input patch (zero-padded at image borders) ---
    for (int p = t; p < IN_H * IN_W; p += NT) {
        int r = p / IN_W, cc = p - r * IN_W;
        int iy = iy0 + r, ix = ix0 + cc;
        float v = 0.f;
        if (iy >= 0 && ix >= 0 && iy < 192 && ix < 192) v = cb[iy * 192 + ix];
        s_in[p] = v;
    }

    // --- conv1 per-pixel state (group-invariant), 5 iters of 192 ---
    int in_off[5], out_off[5];
    float vf[5];
#pragma unroll
    for (int i = 0; i < 5; ++i) {
        int p = t + i * NT;
        int r = p / HT_W, cc = p - r * HT_W;
        int hy = ty0 - 1 + r, hx = tx0 - 1 + cc;
        vf[i] = (hy >= 0 && hy < 96 && hx >= 0 && hx < 96) ? 1.f : 0.f;
        in_off[i] = 2 * r * IN_W + 2 * cc;
        out_off[i] = r * HSTR + cc;
    }

    // thread -> 4 contiguous pixels: row ly, cols lx0..lx0+3
    const int ly = t / 6;             // 0..31
    const int lx0 = (t - ly * 6) * 4; // 0,4,...,20
    // m-domain accumulators: macc[n][pair][j]
    float macc[NCH][2][4];
#pragma unroll
    for (int n = 0; n < NCH; ++n)
#pragma unroll
        for (int pr = 0; pr < 2; ++pr)
#pragma unroll
            for (int j = 0; j < 4; ++j) macc[n][pr][j] = 0.f;

#pragma unroll 1
    for (int g = 0; g < NG; ++g) {
        __syncthreads();   // staging done / prev conv2 reads done

        // conv1 + relu, 8 channels: in9 loaded once per pixel.
#pragma unroll
        for (int i = 0; i < 5; ++i) {
            if (i < 4 || t < NHPX - 4 * NT) {
                const float* ip = s_in + in_off[i];
                float in9[9];
#pragma unroll
                for (int qy = 0; qy < 3; ++qy)
#pragma unroll
                    for (int qx = 0; qx < 3; ++qx)
                        in9[qy * 3 + qx] = ip[qy * IN_W + qx];
#pragma unroll
                for (int cl = 0; cl < CG; ++cl) {
                    const int c = g * CG + cl;
                    float a = b1g[c];
#pragma unroll
                    for (int q = 0; q < 9; ++q)
                        a = fmaf(in9[q], W1g[q * C1 + c], a);
                    s_h[cl * SH_PLANE + out_off[i]] = fmaxf(a, 0.f) * vf[i];
                }
            }
        }
        __syncthreads();   // conv1(g) visible

        // conv2 (Winograd F(2,3) in x): per (cl,ky): 6 ds_reads d0..d5,
        // data transforms (2 pairs x 4 adds), then 4x17 uniform weight
        // loads (s_load) x 2 pairs of FMAs = 136 m-FMAs.
#pragma unroll 1
        for (int cl = 0; cl < CG; ++cl) {
            const int c = g * CG + cl;
            const float* hp = s_h + cl * SH_PLANE + ly * HSTR + lx0;
#pragma unroll
            for (int ky = 0; ky < 3; ++ky) {
                float d[6];
#pragma unroll
                for (int j = 0; j < 6; ++j) d[j] = hp[ky * HSTR + j];
                // pair 0 -> px 0,1 ; pair 1 -> px 2,3
                float pa[4], pb[4];
                pa[0] = d[0] - d[2]; pa[1] = d[1] + d[2];
                pa[2] = d[2] - d[1]; pa[3] = d[1] - d[3];
                pb[0] = d[2] - d[4]; pb[1] = d[3] + d[4];
                pb[2] = d[4] - d[3]; pb[3] = d[3] - d[5];
                const float* wb = Wtg + ((ky * C1 + c) * 4) * NCH;  // uniform
#pragma unroll
                for (int j = 0; j < 4; ++j)
#pragma unroll
                    for (int n = 0; n < NCH; ++n) {
                        const float wv = wb[j * NCH + n];
                        macc[n][0][j] = fmaf(pa[j], wv, macc[n][0][j]);
                        macc[n][1][j] = fmaf(pb[j], wv, macc[n][1][j]);
                    }
            }
        }
    }

    // --- epilogue: inverse transform, per-channel argmax, wave reduce ---
    const int yg = ty0 + ly, xg = tx0 + lx0;
    const int lane = t & 63;
#pragma unroll
    for (int n = 0; n < NCH; ++n) {
        const float bb = b2g[n];
        float o0 = macc[n][0][0] + macc[n][0][1] + macc[n][0][2] + bb;
        float o1 = macc[n][0][1] - macc[n][0][2] - macc[n][0][3] + bb;
        float o2 = macc[n][1][0] + macc[n][1][1] + macc[n][1][2] + bb;
        float o3 = macc[n][1][1] - macc[n][1][2] - macc[n][1][3] + bb;
        // in-thread argmax over 4 px; strict > keeps lowest index on ties
        float mv = o0; int am = 0;
        if (o1 > mv) { mv = o1; am = 1; }
        if (o2 > mv) { mv = o2; am = 2; }
        if (o3 > mv) { mv = o3; am = 3; }
        unsigned long long pk = pack_key(mv, (unsigned)(yg * 96 + xg + am));
#pragma unroll
        for (int off = 32; off; off >>= 1) {
            unsigned long long o = __shfl_down(pk, off, 64);
            if (o > pk) pk = o;
        }
        if (lane == 0) atomicMax(&peaks[b * NCH + n], pk);
    }
}

// One 64-lane wave per (b,n): decode peak, recompute 4 clipped neighbor cms
// values directly (b2 cancels in the sign differences), emit (x,y,val).
__global__ __launch_bounds__(64) void refine_kernel(
    const float* __restrict__ crops, const float* __restrict__ W1g,
    const float* __restrict__ b1g, const float* __restrict__ W2g,
    const unsigned long long* __restrict__ peaks, float* __restrict__ out) {
    const int bn = blockIdx.x;          // 0..128*17-1
    const int b = bn / NCH, n = bn % NCH;
    const int lane = threadIdx.x;

    unsigned long long pk = peaks[bn];
    unsigned key = (unsigned)(pk >> 32);
    unsigned fbits = (key & 0x80000000u) ? (key ^ 0x80000000u) : ~key;
    float val = __uint_as_float(fbits);
    int flat = (int)(~(unsigned)(pk & 0xffffffffu));
    int yi = flat / 96, xi = flat - yi * 96;

    // neighbor j: 0:(yi,xi+1) 1:(yi,xi-1) 2:(yi+1,xi) 3:(yi-1,xi), clipped
    const int j = lane >> 4;
    int yy = yi + ((j == 2) ? 1 : 0) - ((j == 3) ? 1 : 0);
    int xx = xi + ((j == 0) ? 1 : 0) - ((j == 1) ? 1 : 0);
    yy = min(max(yy, 0), 95);
    xx = min(max(xx, 0), 95);

    // hoist 7x7 crops patch: rows 2yy-2..2yy+4, cols 2xx-2..2xx+4
    const float* cb = crops + b * 192 * 192;
    float pat[7][7];
#pragma unroll
    for (int r = 0; r < 7; ++r) {
        int iy = 2 * yy - 2 + r;
#pragma unroll
        for (int s = 0; s < 7; ++s) {
            int ix = 2 * xx - 2 + s;
            pat[r][s] = (iy >= 0 && iy < 192 && ix >= 0 && ix < 192)
                            ? cb[iy * 192 + ix] : 0.f;
        }
    }

    float part = 0.f;
#pragma unroll
    for (int ci = 0; ci < 2; ++ci) {
        const int c = (lane & 15) + ci * 16;
        const float bias = b1g[c];
        float w1[9];
#pragma unroll
        for (int q = 0; q < 9; ++q) w1[q] = W1g[q * C1 + c];
#pragma unroll
        for (int dy = 0; dy < 3; ++dy) {
#pragma unroll
            for (int dx = 0; dx < 3; ++dx) {
                int hy = yy - 1 + dy, hx = xx - 1 + dx;
                if (hy >= 0 && hy < 96 && hx >= 0 && hx < 96) {
                    float a = bias;
#pragma unroll
                    for (int qy = 0; qy < 3; ++qy)
#pragma unroll
                        for (int qx = 0; qx < 3; ++qx)
                            a = fmaf(pat[2 * dy + qy][2 * dx + qx],
                                     w1[qy * 3 + qx], a);
                    float hval = fmaxf(a, 0.f);
                    part = fmaf(hval, W2g[((dy * 3 + dx) * C1 + c) * NCH + n], part);
                }
            }
        }
    }
    // sum the 16 lanes of each neighbor group
    for (int off = 8; off; off >>= 1) part += __shfl_down(part, off, 16);
    float g0 = __shfl(part, 0, 64);
    float g1 = __shfl(part, 16, 64);
    float g2 = __shfl(part, 32, 64);
    float g3 = __shfl(part, 48, 64);

    if (lane == 0) {
        float d0 = g0 - g1, d1 = g2 - g3;
        float sx = (d0 > 0.f) ? 1.f : ((d0 < 0.f) ? -1.f : 0.f);
        float sy = (d1 > 0.f) ? 1.f : ((d1 < 0.f) ? -1.f : 0.f);
        float px = ((float)xi + 0.25f * sx) * 2.f;
        float py = ((float)yi + 0.25f * sy) * 2.f;
        if (!(val >= 0.2f)) {
            px = __int_as_float(0x7fc00000);
            py = __int_as_float(0x7fc00000);
        }
        out[bn * 3 + 0] = px;
        out[bn * 3 + 1] = py;
        out[bn * 3 + 2] = val;
    }
}

extern "C" void kernel_launch(void* const* d_in, const int* in_sizes, int n_in,
                              void* d_out, int out_size, void* d_ws, size_t ws_size,
                              hipStream_t stream) {
    const float* crops = (const float*)d_in[0];
    const float* W1 = (const float*)d_in[1];
    const float* b1 = (const float*)d_in[2];
    const float* W2 = (const float*)d_in[3];
    const float* b2 = (const float*)d_in[4];
    float* out = (float*)d_out;
    unsigned long long* peaks = (unsigned long long*)d_ws;
    float* Wt = (float*)((char*)d_ws + WT_OFF);   // 6528 floats

    hipMemsetAsync(d_ws, 0, 128 * NCH * sizeof(unsigned long long), stream);
    wt_setup_kernel<<<7, 256, 0, stream>>>(W2, Wt);

    dim3 gridB(12, 128);  // 4x3 tiles of 24x32 over 96x96, per image
    conv_peaks_kernel<<<gridB, NT, 0, stream>>>(crops, W1, b1, Wt, b2, peaks);
    refine_kernel<<<128 * NCH, 64, 0, stream>>>(crops, W1, b1, W2, peaks, out);
}